// Round 8
// baseline (72.781 us; speedup 1.0000x reference)
//
#include <hip/hip_runtime.h>
#include <hip/hip_bf16.h>

// Problem dims (fixed by reference)
#define N_IN   1024     // K
#define N_P    1024     // N (= 32*32 lifted grid)
#define FILT   33
#define PAD    16

typedef __attribute__((ext_vector_type(8))) __bf16 bf16x8;
typedef __attribute__((ext_vector_type(4))) float  f32x4;

#define GLB(p) ((const __attribute__((address_space(1))) unsigned int*)(p))
#define LDSP(p) ((__attribute__((address_space(3))) unsigned int*)(p))

__device__ __forceinline__ unsigned int f2bfu(float f) {
    union { __hip_bfloat16 h; unsigned short u; } cv;
    cv.h = __float2bfloat16(f);
    return (unsigned int)cv.u;
}
__device__ __forceinline__ unsigned int pack2bf(float a, float b) {
    return f2bfu(a) | (f2bfu(b) << 16);
}

// ---------------------------------------------------------------------------
// Kernel 1: per-row mean + 1/(std+eps) only (no xn write) -> muinv[row]
// ---------------------------------------------------------------------------
__global__ __launch_bounds__(256)
void stats_kernel(const float* __restrict__ x, float2* __restrict__ muinv)
{
    const int lane = threadIdx.x & 63;
    const int row  = blockIdx.x * 4 + (threadIdx.x >> 6);

    const float4* xr = reinterpret_cast<const float4*>(x + (size_t)row * N_IN);
    float s = 0.f, s2 = 0.f;
#pragma unroll
    for (int i = 0; i < 4; i++) {
        float4 v = xr[i * 64 + lane];
        s  += v.x + v.y + v.z + v.w;
        s2 += v.x * v.x + v.y * v.y + v.z * v.z + v.w * v.w;
    }
#pragma unroll
    for (int off = 32; off > 0; off >>= 1) {
        s  += __shfl_xor(s,  off, 64);
        s2 += __shfl_xor(s2, off, 64);
    }
    const float mu  = s * (1.0f / N_IN);
    const float var = fmaxf(s2 * (1.0f / N_IN) - mu * mu, 0.0f);
    const float inv = 1.0f / (sqrtf(var) + 1e-7f);
    if (lane == 0) muinv[row] = make_float2(mu, inv);
}

// ---------------------------------------------------------------------------
// Kernel 2: Gaussian resolution filter + circular conv along n, fp32 -> bf16
// ---------------------------------------------------------------------------
__global__ __launch_bounds__(256)
void conv_kernel(const float* __restrict__ lm_raw, __hip_bfloat16* __restrict__ lm)
{
    __shared__ float row[N_IN];
    __shared__ float fw[FILT];
    const int tid = threadIdx.x;
    const int p   = blockIdx.x;

    if (tid < FILT) {
        float t = (tid - PAD) * (2.0f / FILT);
        float u = t * 10.0f;            // t / sigma0 (sigma0 = 0.1)
        fw[tid] = expf(-0.5f * u * u);
    }
    reinterpret_cast<float4*>(row)[tid] =
        reinterpret_cast<const float4*>(lm_raw + (size_t)p * N_IN)[tid];
    __syncthreads();

    float fsum = 0.f;
#pragma unroll
    for (int f = 0; f < FILT; f++) fsum += fw[f];
    const float inv = 1.0f / fsum;

    const int n0 = tid * 4;
    float o[4] = {0.f, 0.f, 0.f, 0.f};
#pragma unroll
    for (int f = 0; f < FILT; f++) {
        const float w = fw[f];
#pragma unroll
        for (int j = 0; j < 4; j++)
            o[j] += w * row[(n0 + j + f - PAD) & (N_IN - 1)];
    }
    ushort4 ov;
    ov.x = (unsigned short)f2bfu(o[0] * inv);
    ov.y = (unsigned short)f2bfu(o[1] * inv);
    ov.z = (unsigned short)f2bfu(o[2] * inv);
    ov.w = (unsigned short)f2bfu(o[3] * inv);
    reinterpret_cast<ushort4*>(lm + (size_t)p * N_IN)[tid] = ov;
}

// ---------------------------------------------------------------------------
// Kernel 3: fused GEMM  C[M,N] = normalize(X)[M,K] * B[N,K]^T
// 256x128 tile, BK=32, 512 thr (8 waves 4Mx2N), per-wave 64x64 (acc 4x4).
// A-path FUSED: per tile, each thread loads 16 fp32 of raw x, applies
// (v-mu)*inv, converts to bf16, ds_write_b128 into the swizzled slot
// (key=(row>>1)&3 — same involution the frag reads use).
// B-path: global_load_lds with pre-swizzled source (r5-verified, 0 conflicts).
// 3-deep ring, single barrier/iter, counted vmcnt(1) (vmcnt(0) on final iter):
//   iter t: lgkm(0); vmcnt; barrier; writeA(t+1); loadA(t+2); gloadB(t+2);
//           frag-reads(t); MFMA(t).
// vmcnt(1) at head of iter t leaves only B(t+1) outstanding => A(t+1), B(t)
// landed. Final iter waits vmcnt(0) so B(NT-1) is guaranteed landed.
// ---------------------------------------------------------------------------
__global__ __launch_bounds__(512, 2)
void gemm_fused(const float* __restrict__ X,
                const float2* __restrict__ muinv,
                const __hip_bfloat16* __restrict__ B,
                float* __restrict__ C,
                int M, int N, int K)
{
    constexpr int BK = 32;                  // K-tile; A/B rows are 64B in LDS
    __shared__ char smem[3][24576];         // ring: A[256][64B] (16K) | B[128][64B] (8K)

    const int tid = threadIdx.x;
    const int l   = tid & 63;
    const int w   = tid >> 6;    // 0..7
    const int wm  = w >> 1;      // 0..3  (M direction)
    const int wn  = w & 1;       // 0..1  (N direction)

    // T1: bijective XCD swizzle (nwg=512 divisible by 8)
    const int o    = blockIdx.x;
    const int lin  = (o & 7) * (gridDim.x >> 3) + (o >> 3);
    const int tn   = lin & 7;          // N/128 = 8
    const int tm   = lin >> 3;         // M/256 = 64
    const size_t bm = (size_t)tm * 256;
    const size_t bn = (size_t)tn * 128;

    // ---- A staging geometry (fused normalize, reg -> LDS) ----
    // thread covers row = tid>>1 (0..255), k-half kh = tid&1 (16 fp32)
    const int arow = tid >> 1;
    const int kh   = tid & 1;
    const int akey = (arow >> 1) & 3;
    const float4* gx = reinterpret_cast<const float4*>(
        X + (bm + arow) * (size_t)K + kh * 16);
    const float2 mi  = muinv[bm + arow];
    const float  amu = mi.x, ainv = mi.y;
    const int aoff0 = arow * 64 + 16 * ((kh * 2 + 0) ^ akey);
    const int aoff1 = arow * 64 + 16 * ((kh * 2 + 1) ^ akey);

    float4 a0, a1, a2, a3;   // single areg set: ds_write consumes at issue,
                             // next loads may retarget safely (compiler-tracked WAR)

#define LOADA(t) do {                        \
    const float4* g_ = gx + (size_t)(t) * 8; \
    a0 = g_[0]; a1 = g_[1]; a2 = g_[2]; a3 = g_[3]; } while (0)

#define WRITEA(b) do {                                                   \
    uint4 w0_, w1_;                                                      \
    w0_.x = pack2bf((a0.x - amu) * ainv, (a0.y - amu) * ainv);           \
    w0_.y = pack2bf((a0.z - amu) * ainv, (a0.w - amu) * ainv);           \
    w0_.z = pack2bf((a1.x - amu) * ainv, (a1.y - amu) * ainv);           \
    w0_.w = pack2bf((a1.z - amu) * ainv, (a1.w - amu) * ainv);           \
    w1_.x = pack2bf((a2.x - amu) * ainv, (a2.y - amu) * ainv);           \
    w1_.y = pack2bf((a2.z - amu) * ainv, (a2.w - amu) * ainv);           \
    w1_.z = pack2bf((a3.x - amu) * ainv, (a3.y - amu) * ainv);           \
    w1_.w = pack2bf((a3.z - amu) * ainv, (a3.w - amu) * ainv);           \
    *reinterpret_cast<uint4*>(&smem[(b)][aoff0]) = w0_;                  \
    *reinterpret_cast<uint4*>(&smem[(b)][aoff1]) = w1_; } while (0)

    // ---- B staging geometry (gload_lds, source pre-swizzled) ----
    // LDS linear pos = 16384 + tid*16 -> row = w*16 + (l>>2), slot = l&3
    // swizzle key (row>>1)&3 = (l>>3)&3
    const int bsrow = w * 16 + (l >> 2);
    const int bscol = 16 * ((l & 3) ^ ((l >> 3) & 3));
    const char* gB = (const char*)(B + (bn + bsrow) * (size_t)K) + bscol;

#define STAGEB(t, b) \
    __builtin_amdgcn_global_load_lds(GLB(gB + (size_t)(t) * (BK * 2)), \
                                     LDSP(&smem[(b)][16384] + tid * 16), 16, 0, 0)

    // ---- fragment-read geometry (swizzled ds_read, same involution) ----
    const int lr = l & 15;
    const int kb = l >> 4;
    const int rslot = 16 * (kb ^ ((lr >> 1) & 3));
    const int abase = (wm * 64 + lr) * 64 + rslot;           // + m*1024
    const int bbase = 16384 + (wn * 64 + lr) * 64 + rslot;   // + n*1024

    f32x4 acc[4][4] = {};
    const int NT = K / BK;                               // 32

    // prologue
    LOADA(0);
    STAGEB(0, 0);
    WRITEA(0);                 // compiler inserts vmcnt wait for a0..a3
    LOADA(1);
    STAGEB(1, 1);

    int buf = 0;
    for (int t = 0; t < NT; ++t) {
        asm volatile("s_waitcnt lgkmcnt(0)" ::: "memory");  // frag-reads(t-1)+writes drained
        if (t < NT - 1) asm volatile("s_waitcnt vmcnt(1)" ::: "memory"); // A(t+1), B(t) landed
        else            asm volatile("s_waitcnt vmcnt(0)" ::: "memory"); // B(NT-1) landed
        __builtin_amdgcn_s_barrier();
        __builtin_amdgcn_sched_barrier(0);

        {
            int b1 = buf + 1; if (b1 >= 3) b1 -= 3;
            int b2 = buf + 2; if (b2 >= 3) b2 -= 3;
            if (t + 1 < NT) WRITEA(b1);
            if (t + 2 < NT) { LOADA(t + 2); STAGEB(t + 2, b2); }
        }

        const char* Sb = &smem[buf][0];
        bf16x8 afr[4], bfr[4];
#pragma unroll
        for (int n = 0; n < 4; n++) bfr[n] = *(const bf16x8*)(Sb + bbase + n * 1024);
#pragma unroll
        for (int m = 0; m < 4; m++) afr[m] = *(const bf16x8*)(Sb + abase + m * 1024);

#pragma unroll
        for (int m = 0; m < 4; m++)
#pragma unroll
            for (int n = 0; n < 4; n++)
                acc[m][n] = __builtin_amdgcn_mfma_f32_16x16x32_bf16(afr[m], bfr[n], acc[m][n], 0, 0, 0);

        if (++buf == 3) buf = 0;
    }
#undef LOADA
#undef WRITEA
#undef STAGEB

    // epilogue: C/D layout col = lane&15, row = (lane>>4)*4 + reg  [m89/m91]
    const int crow = (l >> 4) * 4;
    const int ccol = l & 15;
#pragma unroll
    for (int m = 0; m < 4; m++)
#pragma unroll
        for (int n = 0; n < 4; n++) {
#pragma unroll
            for (int r = 0; r < 4; r++) {
                const size_t row = bm + wm * 64 + m * 16 + crow + r;
                const size_t col = bn + wn * 64 + n * 16 + ccol;
                C[row * N + col] = acc[m][n][r];
            }
        }
}

// ---------------------------------------------------------------------------
extern "C" void kernel_launch(void* const* d_in, const int* in_sizes, int n_in,
                              void* d_out, int out_size, void* d_ws, size_t ws_size,
                              hipStream_t stream) {
    const float* x      = (const float*)d_in[0];   // [M, 1024] fp32
    const float* lm_raw = (const float*)d_in[1];   // [32, 32, 1024] fp32
    float* out = (float*)d_out;                    // [M, 32, 32] fp32

    const int M = in_sizes[0] / N_IN;              // 16384

    // workspace layout: lm bf16 [1024,1024] (2 MiB) | muinv float2[M] (128 KiB)
    __hip_bfloat16* lm = (__hip_bfloat16*)d_ws;
    float2* muinv = (float2*)((char*)d_ws + (size_t)N_P * N_IN * 2);

    conv_kernel<<<N_P, 256, 0, stream>>>(lm_raw, lm);
    stats_kernel<<<M / 4, 256, 0, stream>>>(x, muinv);

    const int nblk = (M / 256) * (N_P / 128);      // 64 * 8 = 512
    gemm_fused<<<nblk, dim3(512), 0, stream>>>(x, muinv, lm, out, M, N_P, N_IN);
}

// Round 11
// 64.654 us; speedup vs baseline: 1.1257x; 1.1257x over previous
//
#include <hip/hip_runtime.h>
#include <hip/hip_bf16.h>

// Problem dims (fixed by reference)
#define N_IN   1024     // K
#define N_P    1024     // N (= 32*32 lifted grid)
#define FILT   33
#define PAD    16

typedef __attribute__((ext_vector_type(8))) __bf16 bf16x8;
typedef __attribute__((ext_vector_type(4))) float  f32x4;

#define GLB(p) ((const __attribute__((address_space(1))) unsigned int*)(p))
#define LDSP(p) ((__attribute__((address_space(3))) unsigned int*)(p))

__device__ __forceinline__ unsigned short f2bf(float f) {
    union { __hip_bfloat16 h; unsigned short u; } cv;
    cv.h = __float2bfloat16(f);
    return cv.u;
}

// ---------------------------------------------------------------------------
// Kernel 1: per-row demean + std-normalize, fp32 -> bf16 (r1-proven, ~BW floor)
// ---------------------------------------------------------------------------
__global__ __launch_bounds__(256)
void normalize_kernel(const float* __restrict__ x, __hip_bfloat16* __restrict__ xn)
{
    const int lane = threadIdx.x & 63;
    const int row  = blockIdx.x * 4 + (threadIdx.x >> 6);

    const float4* xr = reinterpret_cast<const float4*>(x + (size_t)row * N_IN);
    float4 v[4];
    float s = 0.f, s2 = 0.f;
#pragma unroll
    for (int i = 0; i < 4; i++) {
        v[i] = xr[i * 64 + lane];
        s  += v[i].x + v[i].y + v[i].z + v[i].w;
        s2 += v[i].x * v[i].x + v[i].y * v[i].y + v[i].z * v[i].z + v[i].w * v[i].w;
    }
#pragma unroll
    for (int off = 32; off > 0; off >>= 1) {
        s  += __shfl_xor(s,  off, 64);
        s2 += __shfl_xor(s2, off, 64);
    }
    const float mu  = s * (1.0f / N_IN);
    const float var = fmaxf(s2 * (1.0f / N_IN) - mu * mu, 0.0f);
    const float inv = 1.0f / (sqrtf(var) + 1e-7f);

    ushort4* outv = reinterpret_cast<ushort4*>(xn + (size_t)row * N_IN);
#pragma unroll
    for (int i = 0; i < 4; i++) {
        ushort4 o;
        o.x = f2bf((v[i].x - mu) * inv);
        o.y = f2bf((v[i].y - mu) * inv);
        o.z = f2bf((v[i].z - mu) * inv);
        o.w = f2bf((v[i].w - mu) * inv);
        outv[i * 64 + lane] = o;
    }
}

// ---------------------------------------------------------------------------
// Kernel 2: Gaussian resolution filter + circular conv along n, fp32 -> bf16
// ---------------------------------------------------------------------------
__global__ __launch_bounds__(256)
void conv_kernel(const float* __restrict__ lm_raw, __hip_bfloat16* __restrict__ lm)
{
    __shared__ float row[N_IN];
    __shared__ float fw[FILT];
    const int tid = threadIdx.x;
    const int p   = blockIdx.x;

    if (tid < FILT) {
        float t = (tid - PAD) * (2.0f / FILT);
        float u = t * 10.0f;            // t / sigma0 (sigma0 = 0.1)
        fw[tid] = expf(-0.5f * u * u);
    }
    reinterpret_cast<float4*>(row)[tid] =
        reinterpret_cast<const float4*>(lm_raw + (size_t)p * N_IN)[tid];
    __syncthreads();

    float fsum = 0.f;
#pragma unroll
    for (int f = 0; f < FILT; f++) fsum += fw[f];
    const float inv = 1.0f / fsum;

    const int n0 = tid * 4;
    float o[4] = {0.f, 0.f, 0.f, 0.f};
#pragma unroll
    for (int f = 0; f < FILT; f++) {
        const float w = fw[f];
#pragma unroll
        for (int j = 0; j < 4; j++)
            o[j] += w * row[(n0 + j + f - PAD) & (N_IN - 1)];
    }
    ushort4 ov;
    ov.x = f2bf(o[0] * inv);
    ov.y = f2bf(o[1] * inv);
    ov.z = f2bf(o[2] * inv);
    ov.w = f2bf(o[3] * inv);
    reinterpret_cast<ushort4*>(lm + (size_t)p * N_IN)[tid] = ov;
}

// ---------------------------------------------------------------------------
// Kernel 3: GEMM  C[M,N] = A[M,K] * B[N,K]^T
// 256x256 tile, BK=32, 512 thr (8 waves 2Mx4N), per-wave 128x64 (acc[8][4]).
// Template-geometry (m201): big wave tile halves LDS-read redundancy
// (A x4, B x2 -> 96KB/CU/iter) and doubles per-barrier MFMA work (32/wave).
// 3-deep LDS ring (3 x 32KB = 96KB), 4 gloads/tile, prefetch distance 2,
// counted s_waitcnt vmcnt(4) (never drains mid-loop; vmcnt(0) last iter).
// Both-sides swizzle involution key=(row>>1)&3 (r5-verified, 0 conflicts).
// T1 bijective XCD swizzle (nwg=256); T5 setprio around MFMA clusters.
// ---------------------------------------------------------------------------
__global__ __launch_bounds__(512, 2)
void gemm_big(const __hip_bfloat16* __restrict__ A,
              const __hip_bfloat16* __restrict__ B,
              float* __restrict__ C,
              int M, int N, int K)
{
    constexpr int BK = 32;                  // K-tile; rows are 64B (4 x 16B slots)
    __shared__ char smem[3][32768];         // ring: A[256][64B] (16K) | B[256][64B] (16K)

    const int tid = threadIdx.x;
    const int l   = tid & 63;
    const int w   = tid >> 6;    // 0..7
    const int wm  = w >> 2;      // 0..1  (M direction, 128 rows each)
    const int wn  = w & 3;       // 0..3  (N direction, 64 cols each)

    // T1: bijective XCD swizzle (nwg=256 divisible by 8)
    const int o    = blockIdx.x;
    const int lin  = (o & 7) * (gridDim.x >> 3) + (o >> 3);
    const int tn   = lin & 3;          // N/256 = 4
    const int tm   = lin >> 2;         // M/256 = 64
    const size_t bm = (size_t)tm * 256;
    const size_t bn = (size_t)tn * 256;

    // ---- staging geometry (per-lane global source, pre-swizzled) ----
    // per gload: 512 thr x 16B = 8KB = 128 rows; row = w*16 + (l>>2) (+128)
    // swizzle key (row>>1)&3 = (l>>3)&3  (w*16 and +128 are 0 mod 8)
    const int srow = w * 16 + (l >> 2);
    const int scol = 16 * ((l & 3) ^ ((l >> 3) & 3));
    const char* gA = (const char*)(A + (bm + srow) * (size_t)K) + scol;
    const char* gB = (const char*)(B + (bn + srow) * (size_t)K) + scol;
    const size_t rowstep = (size_t)128 * K * 2;     // +128 rows (bytes)

    // STAGE(t,b): 4 gloads -> A rows 0-127, 128-255; B rows 0-127, 128-255
#define STAGE(t, b) do {                                                        \
    const char* a0_ = gA + (size_t)(t) * (BK * 2);                              \
    const char* b0_ = gB + (size_t)(t) * (BK * 2);                              \
    char* La_ = &smem[(b)][0]     + w * 1024;                                   \
    char* Lb_ = &smem[(b)][16384] + w * 1024;                                   \
    __builtin_amdgcn_global_load_lds(GLB(a0_),           LDSP(La_),        16, 0, 0); \
    __builtin_amdgcn_global_load_lds(GLB(a0_ + rowstep), LDSP(La_ + 8192), 16, 0, 0); \
    __builtin_amdgcn_global_load_lds(GLB(b0_),           LDSP(Lb_),        16, 0, 0); \
    __builtin_amdgcn_global_load_lds(GLB(b0_ + rowstep), LDSP(Lb_ + 8192), 16, 0, 0); \
} while (0)

    // ---- fragment-read geometry (swizzled ds_read, same involution) ----
    const int lr = l & 15;
    const int kb = l >> 4;                               // k-block of 8 elems
    const int rslot = 16 * (kb ^ ((lr >> 1) & 3));
    const int abase = (wm * 128 + lr) * 64 + rslot;          // + m*1024
    const int bbase = 16384 + (wn * 64 + lr) * 64 + rslot;   // + n*1024

    f32x4 acc[8][4] = {};
    const int NT = K / BK;                               // 32

    STAGE(0, 0);
    STAGE(1, 1);

    int buf = 0;
    for (int t = 0; t < NT; ++t) {
        asm volatile("s_waitcnt lgkmcnt(0)" ::: "memory");  // my prev-iter ds_reads drained
        // tile t's 4 gloads are oldest outstanding; t+1's 4 stay in flight
        if (t < NT - 1) asm volatile("s_waitcnt vmcnt(4)" ::: "memory");
        else            asm volatile("s_waitcnt vmcnt(0)" ::: "memory");
        __builtin_amdgcn_s_barrier();
        __builtin_amdgcn_sched_barrier(0);   // nothing crosses the barrier

        {
            const int t2 = t + 2;
            if (t2 < NT) {
                int b2 = buf + 2; if (b2 >= 3) b2 -= 3;
                STAGE(t2, b2);
            }
        }

        const char* Sb = &smem[buf][0];
        bf16x8 bfr[4], afr[4], afr2[4];
#pragma unroll
        for (int n = 0; n < 4; n++) bfr[n]  = *(const bf16x8*)(Sb + bbase + n * 1024);
#pragma unroll
        for (int m = 0; m < 4; m++) afr[m]  = *(const bf16x8*)(Sb + abase + m * 1024);

        __builtin_amdgcn_s_setprio(1);
#pragma unroll
        for (int m = 0; m < 4; m++)
#pragma unroll
            for (int n = 0; n < 4; n++)
                acc[m][n] = __builtin_amdgcn_mfma_f32_16x16x32_bf16(afr[m], bfr[n], acc[m][n], 0, 0, 0);
        __builtin_amdgcn_s_setprio(0);

#pragma unroll
        for (int m = 0; m < 4; m++) afr2[m] = *(const bf16x8*)(Sb + abase + (m + 4) * 1024);

        __builtin_amdgcn_s_setprio(1);
#pragma unroll
        for (int m = 0; m < 4; m++)
#pragma unroll
            for (int n = 0; n < 4; n++)
                acc[m + 4][n] = __builtin_amdgcn_mfma_f32_16x16x32_bf16(afr2[m], bfr[n], acc[m + 4][n], 0, 0, 0);
        __builtin_amdgcn_s_setprio(0);

        if (++buf == 3) buf = 0;
    }
#undef STAGE

    // epilogue: C/D layout col = lane&15, row = (lane>>4)*4 + reg  [m89/m91]
    const int crow = (l >> 4) * 4;
    const int ccol = l & 15;
#pragma unroll
    for (int m = 0; m < 8; m++)
#pragma unroll
        for (int n = 0; n < 4; n++) {
#pragma unroll
            for (int r = 0; r < 4; r++) {
                const size_t row = bm + wm * 128 + m * 16 + crow + r;
                const size_t col = bn + wn * 64 + n * 16 + ccol;
                C[row * N + col] = acc[m][n][r];
            }
        }
}

// ---------------------------------------------------------------------------
extern "C" void kernel_launch(void* const* d_in, const int* in_sizes, int n_in,
                              void* d_out, int out_size, void* d_ws, size_t ws_size,
                              hipStream_t stream) {
    const float* x      = (const float*)d_in[0];   // [M, 1024] fp32
    const float* lm_raw = (const float*)d_in[1];   // [32, 32, 1024] fp32
    float* out = (float*)d_out;                    // [M, 32, 32] fp32

    const int M = in_sizes[0] / N_IN;              // 16384

    // workspace layout: xn bf16 [M,1024] (32 MiB) | lm bf16 [1024,1024] (2 MiB)
    __hip_bfloat16* xn = (__hip_bfloat16*)d_ws;
    __hip_bfloat16* lm = (__hip_bfloat16*)((char*)d_ws + (size_t)M * N_IN * 2);

    normalize_kernel<<<M / 4, 256, 0, stream>>>(x, xn);
    conv_kernel<<<N_P, 256, 0, stream>>>(lm_raw, lm);

    const int nblk = (M / 256) * (N_P / 256);      // 64 * 4 = 256
    gemm_big<<<nblk, dim3(512), 0, stream>>>(xn, lm, out, M, N_P, N_IN);
}